// Round 1
// baseline (180.596 us; speedup 1.0000x reference)
//
#include <hip/hip_runtime.h>

// ShiftLayer: out[b,t,c] = in[b, t+off[c], c], off per c%3 = {0: identity, 1: t-1, 2: t+1},
// zero padding at t boundaries. B=8, L=8192, C=384 (divisible by 3), fp32 in/out.
//
// v2: t-coarsened. Each thread owns one float4 vector-column v (4 channels) for a
// block of kT=8 consecutive timesteps, rotating {prev,cur,next} rows through
// registers. Loads per output vector drop from 3 -> 1.25 (halo amortized), index
// math amortizes over 8 outputs, stores are nontemporal (output never re-read;
// keep L2 for the input halo shared with neighboring t-blocks).

constexpr int kB = 8;
constexpr int kL = 8192;
constexpr int kC = 384;
constexpr int kV = 4;                    // fp32 elements per 16B vector
constexpr int kCV = kC / kV;             // 96 vectors per (b,t) row
constexpr int kT = 8;                    // timesteps per thread
constexpr int kTB = kL / kT;             // 1024 t-blocks
constexpr int kThreads = 256;
constexpr int kTotalThreads = kB * kTB * kCV;        // 786,432
constexpr int kBlocks = kTotalThreads / kThreads;    // 3072 (exact)

typedef __attribute__((ext_vector_type(4))) float f32x4;

__global__ __launch_bounds__(256) void ShiftLayer_66932770341347_kernel(
    const f32x4* __restrict__ in, f32x4* __restrict__ out) {
  int idx = blockIdx.x * kThreads + threadIdx.x;  // grid is exact, no tail check

  int v = idx % kCV;                 // vector column within the channel row
  int rest = idx / kCV;
  int tb = rest % kTB;               // t-block index
  int b = rest / kTB;                // batch
  int t0 = tb * kT;

  const f32x4* __restrict__ base = in + (long)b * (kL * kCV) + v;
  f32x4* __restrict__ obase = out + (long)b * (kL * kCV) + v;

  const f32x4 zero = {0.f, 0.f, 0.f, 0.f};

  // Base channel of this vector: c0 = 4v; c0 % 3 == v % 3 (4 ≡ 1 mod 3).
  int m0 = v % 3;

  f32x4 prev = (t0 > 0) ? base[(long)(t0 - 1) * kCV] : zero;
  f32x4 cur = base[(long)t0 * kCV];

#pragma unroll
  for (int i = 0; i < kT; ++i) {
    int t = t0 + i;
    f32x4 next = (t + 1 < kL) ? base[(long)(t + 1) * kCV] : zero;

    f32x4 o;
#pragma unroll
    for (int j = 0; j < kV; ++j) {
      int m = m0 + j;                // (v + j) % 3; m0 <= 2, j <= 3 -> m <= 5
      m = (m >= 3) ? m - 3 : m;
      // m==0 -> identity (cur), m==1 -> read t-1 (prev), m==2 -> read t+1 (next)
      o[j] = (m == 0) ? cur[j] : ((m == 1) ? prev[j] : next[j]);
    }
    __builtin_nontemporal_store(o, &obase[(long)t * kCV]);

    prev = cur;
    cur = next;
  }
}

extern "C" void kernel_launch(void* const* d_in, const int* in_sizes, int n_in,
                              void* d_out, int out_size, void* d_ws, size_t ws_size,
                              hipStream_t stream) {
  const f32x4* in = reinterpret_cast<const f32x4*>(d_in[0]);
  f32x4* out = reinterpret_cast<f32x4*>(d_out);
  ShiftLayer_66932770341347_kernel<<<kBlocks, kThreads, 0, stream>>>(in, out);
}

// Round 2
// 174.903 us; speedup vs baseline: 1.0325x; 1.0325x over previous
//
#include <hip/hip_runtime.h>

// ShiftLayer: out[b,t,c] = in[b, t+off[c], c], off per c%3 = {0: identity, 1: t-1, 2: t+1},
// zero padding at t boundaries. B=8, L=8192, C=384 (divisible by 3), fp32 in/out.
//
// v3: t-coarsened (kT=8) with UPFRONT batched loads. v2's register rotation
// serialized the loads (VGPR=20, 1 load in flight, latency-bound at 30% HBM).
// Here all kT+2=10 row loads are issued back-to-back into a fully-unrolled
// register array (10 independent loads per wave in flight), then 8 select+store
// passes. Boundary rows use clamped (always-legal) addresses and are zeroed
// after the fact, so the load block is branchless and uniform.

constexpr int kB = 8;
constexpr int kL = 8192;
constexpr int kC = 384;
constexpr int kV = 4;                    // fp32 elements per 16B vector
constexpr int kCV = kC / kV;             // 96 vectors per (b,t) row
constexpr int kT = 8;                    // timesteps per thread
constexpr int kTB = kL / kT;             // 1024 t-blocks
constexpr int kThreads = 256;
constexpr int kTotalThreads = kB * kTB * kCV;        // 786,432
constexpr int kBlocks = kTotalThreads / kThreads;    // 3072 (exact)

typedef __attribute__((ext_vector_type(4))) float f32x4;

__global__ __launch_bounds__(256) void ShiftLayer_66932770341347_kernel(
    const f32x4* __restrict__ in, f32x4* __restrict__ out) {
  int idx = blockIdx.x * kThreads + threadIdx.x;  // grid is exact, no tail check

  int v = idx % kCV;                 // vector column within the channel row
  int rest = idx / kCV;
  int tb = rest % kTB;               // t-block index
  int b = rest / kTB;                // batch
  int t0 = tb * kT;

  const f32x4* __restrict__ base = in + (long)b * (kL * kCV) + v;
  f32x4* __restrict__ obase = out + (long)b * (kL * kCV) + v;

  const f32x4 zero = {0.f, 0.f, 0.f, 0.f};

  // Batched loads: rows t0-1 .. t0+kT, clamped at the edges (legal address;
  // value overwritten below). All 10 loads are independent -> all in flight.
  f32x4 r[kT + 2];
#pragma unroll
  for (int i = 0; i < kT + 2; ++i) {
    int t = t0 - 1 + i;
    int tc = t < 0 ? 0 : (t >= kL ? kL - 1 : t);
    r[i] = base[(long)tc * kCV];
  }
  if (t0 == 0) r[0] = zero;              // prev of t=0 is the zero pad
  if (t0 + kT == kL) r[kT + 1] = zero;   // next of t=L-1 is the zero pad

  // Base channel of this vector: c0 = 4v; c0 % 3 == v % 3 (4 ≡ 1 mod 3).
  int m0 = v % 3;

#pragma unroll
  for (int i = 0; i < kT; ++i) {
    f32x4 prev = r[i];
    f32x4 cur = r[i + 1];
    f32x4 next = r[i + 2];

    f32x4 o;
#pragma unroll
    for (int j = 0; j < kV; ++j) {
      int m = m0 + j;                // (v + j) % 3; m0 <= 2, j <= 3 -> m <= 5
      m = (m >= 3) ? m - 3 : m;
      // m==0 -> identity (cur), m==1 -> read t-1 (prev), m==2 -> read t+1 (next)
      o[j] = (m == 0) ? cur[j] : ((m == 1) ? prev[j] : next[j]);
    }
    obase[(long)(t0 + i) * kCV] = o;

    (void)prev;
  }
}

extern "C" void kernel_launch(void* const* d_in, const int* in_sizes, int n_in,
                              void* d_out, int out_size, void* d_ws, size_t ws_size,
                              hipStream_t stream) {
  const f32x4* in = reinterpret_cast<const f32x4*>(d_in[0]);
  f32x4* out = reinterpret_cast<f32x4*>(d_out);
  ShiftLayer_66932770341347_kernel<<<kBlocks, kThreads, 0, stream>>>(in, out);
}